// Round 3
// baseline (1078.555 us; speedup 1.0000x reference)
//
#include <hip/hip_runtime.h>

typedef _Float16 f16x8 __attribute__((ext_vector_type(8)));
typedef _Float16 f16x4 __attribute__((ext_vector_type(4)));
typedef float f32x4 __attribute__((ext_vector_type(4)));

#define THREADS 512

static __device__ __forceinline__ f32x4 MFMA(f16x8 a, f16x8 b, f32x4 c) {
  return __builtin_amdgcn_mfma_f32_16x16x32_f16(a, b, c, 0, 0, 0);
}

// ---- weight conversion pre-kernel ------------------------------------------
// ws layout:
//   Wb   : 3 x [224][256] f16  (Wq,Wk,Wv; rows >=200 zero)      @ 0       (344064 B)
//   Wcb  : [224][1024] f16     (conv_w flat; rows >=200 zero)   @ 344064  (458752 B)
//   biasp: 3 x [224] f32       (bq,bk,bv padded w/ zeros)       @ 802816  (2688 B)
__global__ void wcvt(const float* __restrict__ Wq, const float* __restrict__ Wk,
                     const float* __restrict__ Wv, const float* __restrict__ cw,
                     const float* __restrict__ bq, const float* __restrict__ bk,
                     const float* __restrict__ bv,
                     _Float16* __restrict__ Wb,
                     _Float16* __restrict__ Wcb,
                     float* __restrict__ biasp) {
  int gt = blockIdx.x * blockDim.x + threadIdx.x;
  int gs = gridDim.x * blockDim.x;
  const int WN = 224 * 256;
  for (int i = gt; i < WN; i += gs) {
    int n = i >> 8;
    Wb[i]          = (n < 200) ? (_Float16)Wq[i] : (_Float16)0.f;
    Wb[WN + i]     = (n < 200) ? (_Float16)Wk[i] : (_Float16)0.f;
    Wb[2 * WN + i] = (n < 200) ? (_Float16)Wv[i] : (_Float16)0.f;
  }
  for (int i = gt; i < 224 * 1024; i += gs) {
    int o = i >> 10;
    Wcb[i] = (o < 200) ? (_Float16)cw[i] : (_Float16)0.f;
  }
  for (int i = gt; i < 224; i += gs) {
    biasp[i]       = (i < 200) ? bq[i] : 0.f;
    biasp[224 + i] = (i < 200) ? bk[i] : 0.f;
    biasp[448 + i] = (i < 200) ? bv[i] : 0.f;
  }
}

// ---- fused per-batch kernel -------------------------------------------------
// LDS map (bytes):
//   Xl  [64][256] f16 XOR-swizzled (chunk^=(row&7))  @ 0      32768
//   QK  [2][64][40] f16 (Q/K h-slice staging)        @ 32768  20480
//       overlays: Sf [64][65] f32 (16640) ; Po [200][17] f32 (13600)
//   Sb  [64][72] f16  (softmax out)                  @ 53248  9216
//   Vt  [112][72] f16 (V half-tile, [h][m])          @ 62464  16128
// total 78592  -> 2 blocks/CU (<= 80 KiB)
#define LDS_BYTES 78592

__global__ __launch_bounds__(THREADS, 4) void fused_kernel(
    const float* __restrict__ x, const _Float16* __restrict__ Wb,
    const _Float16* __restrict__ Wcb, const float* __restrict__ biasp,
    const float* __restrict__ convb, float* __restrict__ out) {
  extern __shared__ char smem[];
  _Float16* Xl = (_Float16*)smem;            // [64][256] swizzled
  _Float16* QK = (_Float16*)(smem + 32768);  // [2][64][40]
  float*    Sf = (float*)(smem + 32768);     // [64][65]
  float*    Po = (float*)(smem + 32768);     // [200][17]
  _Float16* Sb = (_Float16*)(smem + 53248);  // [64][72]
  _Float16* Vt = (_Float16*)(smem + 62464);  // [112][72]

  const int b = blockIdx.x;
  const int tid = threadIdx.x;
  const int lane = tid & 63;
  const int wave = tid >> 6;
  const int li = lane & 15;
  const int g  = lane >> 4;

  // ---- Phase A: load x[b] -> f16 LDS, XOR-swizzled chunks ----
  const float* xb = x + (size_t)b * 16384;
#pragma unroll
  for (int jj = 0; jj < 8; jj++) {
    int f = tid + 512 * jj;         // float4 index 0..4095
    float4 v = ((const float4*)xb)[f];
    int l = f >> 6;
    int c = (f & 63) >> 1;
    int sub = (f & 1) * 4;
    f16x4 h;
    h.x = (_Float16)v.x; h.y = (_Float16)v.y;
    h.z = (_Float16)v.z; h.w = (_Float16)v.w;
    *(f16x4*)(Xl + l * 256 + ((c ^ (l & 7)) << 3) + sub) = h;
  }
  __syncthreads();

  // ---- Phase B+C fused: h-sliced Q/K projection + S accumulation ----
  f32x4 sacc0 = {0.f, 0.f, 0.f, 0.f};
  f32x4 sacc1 = {0.f, 0.f, 0.f, 0.f};
  const int t0 = 2 * wave;           // this wave's S tiles: t0, t0+1
  for (int sl = 0; sl < 7; sl++) {
#pragma unroll
    for (int uu = 0; uu < 2; uu++) {
      int u = 2 * wave + uu;
      int p  = u >> 3;               // 0=Q, 1=K
      int mt = (u & 7) >> 1;
      int hh = u & 1;
      int n = sl * 32 + hh * 16 + li;
      const _Float16* wrow = Wb + p * 57344 + n * 256 + 8 * g;
      f32x4 acc = {0.f, 0.f, 0.f, 0.f};
      int arow = mt * 16 + li;
#pragma unroll
      for (int kk = 0; kk < 8; kk++) {
        f16x8 af = *(const f16x8*)(Xl + arow * 256 + (((g + 4 * kk) ^ (arow & 7)) << 3));
        f16x8 bf = *(const f16x8*)(wrow + 32 * kk);
        acc = MFMA(af, bf, acc);
      }
      float bias = biasp[p * 224 + n];
#pragma unroll
      for (int r = 0; r < 4; r++) {
        float v = acc[r] + bias;
        v = v > 0.f ? v : 0.f;
        QK[p * 2560 + (mt * 16 + 4 * g + r) * 40 + hh * 16 + li] = (_Float16)v;
      }
    }
    __syncthreads();
    {
      int mt = t0 >> 2, nt = t0 & 3;
      f16x8 qa = *(const f16x8*)(QK + (mt * 16 + li) * 40 + 8 * g);
      f16x8 kb = *(const f16x8*)(QK + 2560 + (nt * 16 + li) * 40 + 8 * g);
      sacc0 = MFMA(qa, kb, sacc0);
      int t1 = t0 + 1;
      int mt1 = t1 >> 2, nt1 = t1 & 3;
      f16x8 qa1 = *(const f16x8*)(QK + (mt1 * 16 + li) * 40 + 8 * g);
      f16x8 kb1 = *(const f16x8*)(QK + 2560 + (nt1 * 16 + li) * 40 + 8 * g);
      sacc1 = MFMA(qa1, kb1, sacc1);
    }
    __syncthreads();
  }

  // ---- write S tiles -> Sf (overlays QK region; safe after last barrier) ----
#pragma unroll
  for (int tt = 0; tt < 2; tt++) {
    int t = t0 + tt;
    int mt = t >> 2, nt = t & 3;
    f32x4 a = tt ? sacc1 : sacc0;
#pragma unroll
    for (int r = 0; r < 4; r++)
      Sf[(mt * 16 + 4 * g + r) * 65 + nt * 16 + li] = a[r];
  }
  __syncthreads();

  // ---- softmax over axis l (dim=1): per column m ----
  {
    int m = tid >> 3, r = tid & 7;
    float vals[8];
    float mx = -1e30f;
#pragma unroll
    for (int i = 0; i < 8; i++) {
      float v = Sf[(r + 8 * i) * 65 + m];
      vals[i] = v;
      mx = fmaxf(mx, v);
    }
    mx = fmaxf(mx, __shfl_xor(mx, 1));
    mx = fmaxf(mx, __shfl_xor(mx, 2));
    mx = fmaxf(mx, __shfl_xor(mx, 4));
    float s = 0.f;
#pragma unroll
    for (int i = 0; i < 8; i++) {
      vals[i] = __expf(vals[i] - mx);
      s += vals[i];
    }
    s += __shfl_xor(s, 1);
    s += __shfl_xor(s, 2);
    s += __shfl_xor(s, 4);
    float inv = 1.0f / s;
#pragma unroll
    for (int i = 0; i < 8; i++)
      Sb[(r + 8 * i) * 72 + m] = (_Float16)(vals[i] * inv);
  }
  __syncthreads();

  // ---- conv (plain-stores Po) + V halves + PV (atomicAdd Po) ----
  for (int half = 0; half < 2; half++) {
    if (half == 0) {
      // conv as GEMM [16 x 1024] * [1024 x 224] -> Po[o][t]
      for (int nt = wave; nt < 14; nt += 8) {
        int o = nt * 16 + li;
        const _Float16* wrow = Wcb + o * 1024 + 8 * g;
        f32x4 acc = {0.f, 0.f, 0.f, 0.f};
#pragma unroll 4
        for (int kk = 0; kk < 32; kk++) {
          int i1 = kk * 8 + 2 * g;
          union { f16x4 h[2]; f16x8 v; } af;
          {
            int pos = 64 * i1 + 4 * li;
            int row = pos >> 8, d = pos & 255;
            af.h[0] = *(const f16x4*)(Xl + row * 256 +
                        (((d >> 3) ^ (row & 7)) << 3) + (d & 7));
          }
          {
            int pos = 64 * (i1 + 1) + 4 * li;
            int row = pos >> 8, d = pos & 255;
            af.h[1] = *(const f16x4*)(Xl + row * 256 +
                        (((d >> 3) ^ (row & 7)) << 3) + (d & 7));
          }
          acc = MFMA(af.v, *(const f16x8*)(wrow + 32 * kk), acc);
        }
        if (o < 200) {
#pragma unroll
          for (int r = 0; r < 4; r++) Po[o * 17 + 4 * g + r] = acc[r];
        }
      }
    }
    // V projection for this half: V[m][h], h in [half*112, half*112+112)
    for (int u = wave; u < 28; u += 8) {
      int mt = u / 7, ht = u % 7;
      int hloc = ht * 16 + li;
      int n = half * 112 + hloc;
      const _Float16* wrow = Wb + 2 * 57344 + n * 256 + 8 * g;
      f32x4 acc = {0.f, 0.f, 0.f, 0.f};
      int arow = mt * 16 + li;
#pragma unroll
      for (int kk = 0; kk < 8; kk++) {
        f16x8 af = *(const f16x8*)(Xl + arow * 256 + (((g + 4 * kk) ^ (arow & 7)) << 3));
        acc = MFMA(af, *(const f16x8*)(wrow + 32 * kk), acc);
      }
      float bias = biasp[448 + n];
#pragma unroll
      for (int r = 0; r < 4; r++) {
        float v = acc[r] + bias;
        v = v > 0.f ? v : 0.f;
        Vt[hloc * 72 + mt * 16 + 4 * g + r] = (_Float16)v;
      }
    }
    __syncthreads();
    // PV: self_att contributions pooled directly into Po
    for (int u = wave; u < 28; u += 8) {
      int mt = u / 7, ntl = u % 7;
      f32x4 acc = {0.f, 0.f, 0.f, 0.f};
#pragma unroll
      for (int kk = 0; kk < 2; kk++) {
        f16x8 pa = *(const f16x8*)(Sb + (mt * 16 + li) * 72 + 32 * kk + 8 * g);
        f16x8 vb = *(const f16x8*)(Vt + (ntl * 16 + li) * 72 + 32 * kk + 8 * g);
        acc = MFMA(pa, vb, acc);
      }
      int h = half * 112 + ntl * 16 + li;
      if (h < 200) {
#pragma unroll
        for (int r = 0; r < 4; r++) {
          int l = mt * 16 + 4 * g + r;
          int flat = l * 200 + h;
          atomicAdd(&Po[(flat >> 6) * 17 + (flat & 15)], 0.25f * acc[r]);
        }
      }
    }
    __syncthreads();
  }

  // ---- store: out flat [200][16] = Po + conv bias ----
  float* ob = out + (size_t)b * 3200;
  for (int t = tid; t < 3200; t += THREADS) {
    int c = t >> 4;
    ob[t] = Po[c * 17 + (t & 15)] + convb[c];
  }
}

// ---- launch -----------------------------------------------------------------
extern "C" void kernel_launch(void* const* d_in, const int* in_sizes, int n_in,
                              void* d_out, int out_size, void* d_ws, size_t ws_size,
                              hipStream_t stream) {
  const float* x  = (const float*)d_in[0];
  const float* Wq = (const float*)d_in[1];
  const float* bq = (const float*)d_in[2];
  const float* Wk = (const float*)d_in[3];
  const float* bk = (const float*)d_in[4];
  const float* Wv = (const float*)d_in[5];
  const float* bv = (const float*)d_in[6];
  const float* cw = (const float*)d_in[7];
  const float* cb = (const float*)d_in[8];

  char* ws = (char*)d_ws;
  _Float16* Wb  = (_Float16*)ws;             // 344064 B
  _Float16* Wcb = (_Float16*)(ws + 344064);  // 458752 B
  float* biasp  = (float*)(ws + 802816);     // 2688 B

  hipLaunchKernelGGL(wcvt, dim3(512), dim3(256), 0, stream,
                     Wq, Wk, Wv, cw, bq, bk, bv, Wb, Wcb, biasp);

  hipFuncSetAttribute((const void*)fused_kernel,
                      hipFuncAttributeMaxDynamicSharedMemorySize, LDS_BYTES);
  hipLaunchKernelGGL(fused_kernel, dim3(4096), dim3(THREADS), LDS_BYTES, stream,
                     x, Wb, Wcb, biasp, cb, (float*)d_out);
}

// Round 4
// 798.743 us; speedup vs baseline: 1.3503x; 1.3503x over previous
//
#include <hip/hip_runtime.h>

typedef _Float16 f16x8 __attribute__((ext_vector_type(8)));
typedef _Float16 f16x4 __attribute__((ext_vector_type(4)));
typedef float f32x4 __attribute__((ext_vector_type(4)));

#define THREADS 512

static __device__ __forceinline__ f32x4 MFMA(f16x8 a, f16x8 b, f32x4 c) {
  return __builtin_amdgcn_mfma_f32_16x16x32_f16(a, b, c, 0, 0, 0);
}

// ---- weight conversion pre-kernel ------------------------------------------
// ws layout:
//   Wb   : 3 x [256][256] f16  (Wq,Wk,Wv; rows >=200 zero)      @ 0       (393216 B)
//   Wcb  : [224][1024] f16     (conv_w flat; rows >=200 zero)   @ 393216  (458752 B)
//   biasp: 3 x [256] f32       (bq,bk,bv padded w/ zeros)       @ 851968  (3072 B)
__global__ void wcvt(const float* __restrict__ Wq, const float* __restrict__ Wk,
                     const float* __restrict__ Wv, const float* __restrict__ cw,
                     const float* __restrict__ bq, const float* __restrict__ bk,
                     const float* __restrict__ bv,
                     _Float16* __restrict__ Wb,
                     _Float16* __restrict__ Wcb,
                     float* __restrict__ biasp) {
  int gt = blockIdx.x * blockDim.x + threadIdx.x;
  int gs = gridDim.x * blockDim.x;
  const int WN = 256 * 256;
  for (int i = gt; i < WN; i += gs) {
    int n = i >> 8;
    Wb[i]          = (n < 200) ? (_Float16)Wq[i] : (_Float16)0.f;
    Wb[WN + i]     = (n < 200) ? (_Float16)Wk[i] : (_Float16)0.f;
    Wb[2 * WN + i] = (n < 200) ? (_Float16)Wv[i] : (_Float16)0.f;
  }
  for (int i = gt; i < 224 * 1024; i += gs) {
    int o = i >> 10;
    Wcb[i] = (o < 200) ? (_Float16)cw[i] : (_Float16)0.f;
  }
  for (int i = gt; i < 256; i += gs) {
    biasp[i]       = (i < 200) ? bq[i] : 0.f;
    biasp[256 + i] = (i < 200) ? bk[i] : 0.f;
    biasp[512 + i] = (i < 200) ? bv[i] : 0.f;
  }
}

// ---- fused per-batch kernel -------------------------------------------------
// LDS map (bytes):
//   Xl  [64][256] f16 XOR-swizzled (chunk^=(row&7))   @ 0      32768
//   QK  [2 buf][2 p][64][70] f16 (proj slice staging) @ 32768  35840 (ends 68608)
//     overlays after B+C:
//       Sf [64][67] f32 (17152, fits buf0=17920)      @ 32768
//     overlays in tail:
//       Vt [112][70] f16 (15680, ends 48448)          @ 32768
//       Po [200][17] f32 (13600, ends 62048)          @ 48448
//   Sb  [64][70] f16 (softmax out)                    @ 68608  8960
// total 77568 -> 2 blocks/CU
#define LDS_BYTES 77568

__global__ __launch_bounds__(THREADS, 4) void fused_kernel(
    const float* __restrict__ x, const _Float16* __restrict__ Wb,
    const _Float16* __restrict__ Wcb, const float* __restrict__ biasp,
    const float* __restrict__ convb, float* __restrict__ out) {
  extern __shared__ char smem[];
  _Float16* Xl = (_Float16*)smem;             // [64][256] swizzled
  _Float16* QK = (_Float16*)(smem + 32768);   // [2][2][64][70]
  float*    Sf = (float*)(smem + 32768);      // [64][67]
  _Float16* Vt = (_Float16*)(smem + 32768);   // [112][70]
  float*    Po = (float*)(smem + 48448);      // [200][17]
  _Float16* Sb = (_Float16*)(smem + 68608);   // [64][70]

  const int b = blockIdx.x;
  const int tid = threadIdx.x;
  const int lane = tid & 63;
  const int wave = tid >> 6;
  const int li = lane & 15;
  const int g  = lane >> 4;

  // ---- Phase A: load x[b] -> f16 LDS, XOR-swizzled chunks ----
  const float* xb = x + (size_t)b * 16384;
#pragma unroll
  for (int jj = 0; jj < 8; jj++) {
    int f = tid + 512 * jj;         // float4 index 0..4095
    float4 v = ((const float4*)xb)[f];
    int l = f >> 6;
    int c = (f & 63) >> 1;
    int sub = (f & 1) * 4;
    f16x4 h;
    h.x = (_Float16)v.x; h.y = (_Float16)v.y;
    h.z = (_Float16)v.z; h.w = (_Float16)v.w;
    *(f16x4*)(Xl + l * 256 + ((c ^ (l & 7)) << 3) + sub) = h;
  }

  // ---- Phase B+C: h-sliced Q/K proj (double-buffered) + S in registers ----
  f32x4 sacc0 = {0.f, 0.f, 0.f, 0.f};
  f32x4 sacc1 = {0.f, 0.f, 0.f, 0.f};
  const int mt0 = wave >> 1;          // this wave's S tiles: (mt0,nt0),(mt0,nt0+1)
  const int nt0 = (2 * wave) & 3;

  auto proj_slice = [&](int sl, int bsel) {
    int p = wave >> 2, ntl = wave & 3;
    int n = sl * 64 + ntl * 16 + li;
    const _Float16* wrow = Wb + p * 65536 + n * 256 + 8 * g;
    f16x8 bfr[8];
#pragma unroll
    for (int kk = 0; kk < 8; kk++) bfr[kk] = *(const f16x8*)(wrow + 32 * kk);
    float bias = biasp[p * 256 + n];
    _Float16* dst = QK + bsel * 8960 + p * 4480;
#pragma unroll
    for (int mt = 0; mt < 4; mt++) {
      f32x4 acc = {0.f, 0.f, 0.f, 0.f};
      int arow = mt * 16 + li;
#pragma unroll
      for (int kk = 0; kk < 8; kk++) {
        f16x8 af = *(const f16x8*)(Xl + arow * 256 + (((g + 4 * kk) ^ (arow & 7)) << 3));
        acc = MFMA(af, bfr[kk], acc);
      }
#pragma unroll
      for (int r = 0; r < 4; r++) {
        float v = acc[r] + bias;
        v = v > 0.f ? v : 0.f;
        dst[(mt * 16 + 4 * g + r) * 70 + ntl * 16 + li] = (_Float16)v;
      }
    }
  };

  auto accum_slice = [&](int bsel) {
    const _Float16* qb = QK + bsel * 8960;
    const _Float16* kb = qb + 4480;
#pragma unroll
    for (int kk = 0; kk < 2; kk++) {
      f16x8 a0 = *(const f16x8*)(qb + (mt0 * 16 + li) * 70 + 32 * kk + 8 * g);
      f16x8 b0 = *(const f16x8*)(kb + (nt0 * 16 + li) * 70 + 32 * kk + 8 * g);
      sacc0 = MFMA(a0, b0, sacc0);
      f16x8 b1 = *(const f16x8*)(kb + ((nt0 + 1) * 16 + li) * 70 + 32 * kk + 8 * g);
      sacc1 = MFMA(a0, b1, sacc1);
    }
  };

  __syncthreads();           // Xl ready
  proj_slice(0, 0);
  __syncthreads();
  proj_slice(1, 1); accum_slice(0);
  __syncthreads();
  proj_slice(2, 0); accum_slice(1);
  __syncthreads();
  proj_slice(3, 1); accum_slice(0);
  __syncthreads();
  accum_slice(1);

  // ---- write S tiles -> Sf (overlays buf0; safe: buf0 last read before bar) ----
#pragma unroll
  for (int tt = 0; tt < 2; tt++) {
    f32x4 a = tt ? sacc1 : sacc0;
    int nt = nt0 + tt;
#pragma unroll
    for (int r = 0; r < 4; r++)
      Sf[(mt0 * 16 + 4 * g + r) * 67 + nt * 16 + li] = a[r];
  }
  __syncthreads();

  // ---- softmax over axis l (dim=1): per column m ----
  {
    int m = tid >> 3, r = tid & 7;
    float vals[8];
    float mx = -1e30f;
#pragma unroll
    for (int i = 0; i < 8; i++) {
      float v = Sf[(r + 8 * i) * 67 + m];
      vals[i] = v;
      mx = fmaxf(mx, v);
    }
    mx = fmaxf(mx, __shfl_xor(mx, 1));
    mx = fmaxf(mx, __shfl_xor(mx, 2));
    mx = fmaxf(mx, __shfl_xor(mx, 4));
    float s = 0.f;
#pragma unroll
    for (int i = 0; i < 8; i++) {
      vals[i] = __expf(vals[i] - mx);
      s += vals[i];
    }
    s += __shfl_xor(s, 1);
    s += __shfl_xor(s, 2);
    s += __shfl_xor(s, 4);
    float inv = 1.0f / s;
#pragma unroll
    for (int i = 0; i < 8; i++)
      Sb[(r + 8 * i) * 70 + m] = (_Float16)(vals[i] * inv);
  }
  __syncthreads();

  // ---- tail: conv + V halves + PV scatter-pool ----
  for (int half = 0; half < 2; half++) {
    if (half == 0) {
      // pooled units: u<14 conv, u in [14,21) V-proj half0
      for (int u = wave; u < 21; u += 8) {
        if (u < 14) {
          int o = u * 16 + li;
          const _Float16* wrow = Wcb + o * 1024 + 8 * g;
          f32x4 acc = {0.f, 0.f, 0.f, 0.f};
#pragma unroll 4
          for (int kk = 0; kk < 32; kk++) {
            int i1 = kk * 8 + 2 * g;
            union { f16x4 h[2]; f16x8 v; } af;
            {
              int pos = 64 * i1 + 4 * li;
              int row = pos >> 8, d = pos & 255;
              af.h[0] = *(const f16x4*)(Xl + row * 256 +
                          (((d >> 3) ^ (row & 7)) << 3) + (d & 7));
            }
            {
              int pos = 64 * (i1 + 1) + 4 * li;
              int row = pos >> 8, d = pos & 255;
              af.h[1] = *(const f16x4*)(Xl + row * 256 +
                          (((d >> 3) ^ (row & 7)) << 3) + (d & 7));
            }
            acc = MFMA(af.v, *(const f16x8*)(wrow + 32 * kk), acc);
          }
          if (o < 200) {
#pragma unroll
            for (int r = 0; r < 4; r++) Po[o * 17 + 4 * g + r] = acc[r];
          }
        } else {
          int hloc = (u - 14) * 16 + li;      // V-proj half0: n = hloc
          const _Float16* wrow = Wb + 131072 + hloc * 256 + 8 * g;
          f16x8 bfr[8];
#pragma unroll
          for (int kk = 0; kk < 8; kk++) bfr[kk] = *(const f16x8*)(wrow + 32 * kk);
          float bias = biasp[512 + hloc];
#pragma unroll
          for (int mt = 0; mt < 4; mt++) {
            f32x4 acc = {0.f, 0.f, 0.f, 0.f};
            int arow = mt * 16 + li;
#pragma unroll
            for (int kk = 0; kk < 8; kk++) {
              f16x8 af = *(const f16x8*)(Xl + arow * 256 + (((g + 4 * kk) ^ (arow & 7)) << 3));
              acc = MFMA(af, bfr[kk], acc);
            }
            f16x4 hv;
#pragma unroll
            for (int r = 0; r < 4; r++) {
              float v = acc[r] + bias;
              hv[r] = (_Float16)(v > 0.f ? v : 0.f);
            }
            *(f16x4*)(Vt + hloc * 70 + mt * 16 + 4 * g) = hv;
          }
        }
      }
    } else {
      // V-proj half1: 7 units
      if (wave < 7) {
        int hloc = wave * 16 + li;
        int n = 112 + hloc;
        const _Float16* wrow = Wb + 131072 + n * 256 + 8 * g;
        f16x8 bfr[8];
#pragma unroll
        for (int kk = 0; kk < 8; kk++) bfr[kk] = *(const f16x8*)(wrow + 32 * kk);
        float bias = biasp[512 + n];
#pragma unroll
        for (int mt = 0; mt < 4; mt++) {
          f32x4 acc = {0.f, 0.f, 0.f, 0.f};
          int arow = mt * 16 + li;
#pragma unroll
          for (int kk = 0; kk < 8; kk++) {
            f16x8 af = *(const f16x8*)(Xl + arow * 256 + (((g + 4 * kk) ^ (arow & 7)) << 3));
            acc = MFMA(af, bfr[kk], acc);
          }
          f16x4 hv;
#pragma unroll
          for (int r = 0; r < 4; r++) {
            float v = acc[r] + bias;
            hv[r] = (_Float16)(v > 0.f ? v : 0.f);
          }
          *(f16x4*)(Vt + hloc * 70 + mt * 16 + 4 * g) = hv;
        }
      }
    }
    __syncthreads();
    // PV: self_att contributions pooled into Po via LDS atomics
    for (int u = wave; u < 28; u += 8) {
      int mt = u / 7, ntl = u % 7;
      f32x4 acc = {0.f, 0.f, 0.f, 0.f};
#pragma unroll
      for (int kk = 0; kk < 2; kk++) {
        f16x8 pa = *(const f16x8*)(Sb + (mt * 16 + li) * 70 + 32 * kk + 8 * g);
        f16x8 vb = *(const f16x8*)(Vt + (ntl * 16 + li) * 70 + 32 * kk + 8 * g);
        acc = MFMA(pa, vb, acc);
      }
      int h = half * 112 + ntl * 16 + li;
      if (h < 200) {
#pragma unroll
        for (int r = 0; r < 4; r++) {
          int l = mt * 16 + 4 * g + r;
          int f = l * 200 + h;
          atomicAdd(&Po[(f >> 6) * 17 + (f & 15)], 0.25f * acc[r]);
        }
      }
    }
    __syncthreads();
  }

  // ---- store: out flat [200][16] = Po + conv bias ----
  float* ob = out + (size_t)b * 3200;
  for (int t = tid; t < 3200; t += THREADS) {
    int c = t >> 4;
    ob[t] = Po[c * 17 + (t & 15)] + convb[c];
  }
}

// ---- launch -----------------------------------------------------------------
extern "C" void kernel_launch(void* const* d_in, const int* in_sizes, int n_in,
                              void* d_out, int out_size, void* d_ws, size_t ws_size,
                              hipStream_t stream) {
  const float* x  = (const float*)d_in[0];
  const float* Wq = (const float*)d_in[1];
  const float* bq = (const float*)d_in[2];
  const float* Wk = (const float*)d_in[3];
  const float* bk = (const float*)d_in[4];
  const float* Wv = (const float*)d_in[5];
  const float* bv = (const float*)d_in[6];
  const float* cw = (const float*)d_in[7];
  const float* cb = (const float*)d_in[8];

  char* ws = (char*)d_ws;
  _Float16* Wb  = (_Float16*)ws;             // 393216 B
  _Float16* Wcb = (_Float16*)(ws + 393216);  // 458752 B
  float* biasp  = (float*)(ws + 851968);     // 3072 B

  hipLaunchKernelGGL(wcvt, dim3(512), dim3(256), 0, stream,
                     Wq, Wk, Wv, cw, bq, bk, bv, Wb, Wcb, biasp);

  hipFuncSetAttribute((const void*)fused_kernel,
                      hipFuncAttributeMaxDynamicSharedMemorySize, LDS_BYTES);
  hipLaunchKernelGGL(fused_kernel, dim3(4096), dim3(THREADS), LDS_BYTES, stream,
                     x, Wb, Wcb, biasp, cb, (float*)d_out);
}

// Round 5
// 624.722 us; speedup vs baseline: 1.7265x; 1.2786x over previous
//
#include <hip/hip_runtime.h>

typedef _Float16 f16x8 __attribute__((ext_vector_type(8)));
typedef _Float16 f16x4 __attribute__((ext_vector_type(4)));
typedef float f32x4 __attribute__((ext_vector_type(4)));

static __device__ __forceinline__ f32x4 MFMA(f16x8 a, f16x8 b, f32x4 c) {
  return __builtin_amdgcn_mfma_f32_16x16x32_f16(a, b, c, 0, 0, 0);
}

// ---- weight conversion pre-kernel ------------------------------------------
// ws layout:
//   Wb   : 3 x [224][256] f16  (Wq,Wk,Wv; rows >=200 zero)      @ 0       (344064 B)
//   Wcb  : [224][1024] f16     (conv_w flat; rows >=200 zero)   @ 344064  (458752 B)
//   biasp: 3 x [224] f32       (bq,bk,bv padded w/ zeros)       @ 802816  (2688 B)
//   Qg   : [4096][64][224] f16                                  @ 805888
//   Kg   : [4096][64][224] f16                                  @ 805888+117440512
//   Vtg  : [4096][224][64] f16                                  @ 805888+234881024
__global__ void wcvt(const float* __restrict__ Wq, const float* __restrict__ Wk,
                     const float* __restrict__ Wv, const float* __restrict__ cw,
                     const float* __restrict__ bq, const float* __restrict__ bk,
                     const float* __restrict__ bv,
                     _Float16* __restrict__ Wb,
                     _Float16* __restrict__ Wcb,
                     float* __restrict__ biasp) {
  int gt = blockIdx.x * blockDim.x + threadIdx.x;
  int gs = gridDim.x * blockDim.x;
  const int WN = 224 * 256;
  for (int i = gt; i < WN; i += gs) {
    int n = i >> 8;
    Wb[i]          = (n < 200) ? (_Float16)Wq[i] : (_Float16)0.f;
    Wb[WN + i]     = (n < 200) ? (_Float16)Wk[i] : (_Float16)0.f;
    Wb[2 * WN + i] = (n < 200) ? (_Float16)Wv[i] : (_Float16)0.f;
  }
  for (int i = gt; i < 224 * 1024; i += gs) {
    int o = i >> 10;
    Wcb[i] = (o < 200) ? (_Float16)cw[i] : (_Float16)0.f;
  }
  for (int i = gt; i < 224; i += gs) {
    biasp[i]       = (i < 200) ? bq[i] : 0.f;
    biasp[224 + i] = (i < 200) ? bk[i] : 0.f;
    biasp[448 + i] = (i < 200) ? bv[i] : 0.f;
  }
}

// ---- K1: projections + conv for 4 batches per block -------------------------
// LDS: Xl 4 x [64][264] f16 = 135168 B. One barrier total.
// 56 units (42 proj: p=u/14, nt=u%14; 14 conv): each loads W-frags once,
// computes 128 MFMAs (4 batches x 4 m-tiles x 8 kk  |  32 kk x 4 batches).
__global__ __launch_bounds__(512, 2) void k1_proj_conv(
    const float* __restrict__ x, const _Float16* __restrict__ Wb,
    const _Float16* __restrict__ Wcb, const float* __restrict__ biasp,
    const float* __restrict__ convb,
    _Float16* __restrict__ Qg, _Float16* __restrict__ Kg,
    _Float16* __restrict__ Vtg, float* __restrict__ out) {
  extern __shared__ char smem[];
  _Float16* Xl = (_Float16*)smem;  // 4 x [64][264]
  const int tid = threadIdx.x, lane = tid & 63, wave = tid >> 6;
  const int li = lane & 15, g = lane >> 4;
  const int b0 = blockIdx.x * 4;

  // stage x for 4 batches (coalesced float4, f32->f16)
  const float* xb = x + (size_t)b0 * 16384;
#pragma unroll
  for (int j = 0; j < 32; j++) {
    int f = tid + 512 * j;               // float4 idx over 4 batches
    float4 v = ((const float4*)xb)[f];
    int bt = f >> 12, rem = f & 4095, l = rem >> 6, c4 = rem & 63;
    f16x4 h;
    h.x = (_Float16)v.x; h.y = (_Float16)v.y;
    h.z = (_Float16)v.z; h.w = (_Float16)v.w;
    *(f16x4*)(Xl + bt * 16896 + l * 264 + c4 * 4) = h;
  }
  __syncthreads();

  for (int i = 0; i < 7; i++) {
    int u = wave + 8 * i;
    if (u < 42) {
      // ---- projection unit ----
      int p = u / 14, nt = u % 14, n = nt * 16 + li;
      const _Float16* wrow = Wb + p * 57344 + n * 256 + 8 * g;
      f16x8 bfr[8];
#pragma unroll
      for (int kk = 0; kk < 8; kk++) bfr[kk] = *(const f16x8*)(wrow + 32 * kk);
      float bias = biasp[p * 224 + n];
#pragma unroll
      for (int bt = 0; bt < 4; bt++) {
        const _Float16* xt = Xl + bt * 16896;
        f32x4 acc[4] = {};
#pragma unroll
        for (int kk = 0; kk < 8; kk++) {
#pragma unroll
          for (int mt = 0; mt < 4; mt++) {
            f16x8 af = *(const f16x8*)(xt + (mt * 16 + li) * 264 + 32 * kk + 8 * g);
            acc[mt] = MFMA(af, bfr[kk], acc[mt]);
          }
        }
        size_t bb = (size_t)(b0 + bt) * 14336;
#pragma unroll
        for (int mt = 0; mt < 4; mt++) {
#pragma unroll
          for (int r = 0; r < 4; r++) {
            int l = mt * 16 + 4 * g + r;
            float v = acc[mt][r] + bias;
            _Float16 hv = (_Float16)(v > 0.f ? v : 0.f);
            if (p == 0)      Qg[bb + l * 224 + n] = hv;
            else if (p == 1) Kg[bb + l * 224 + n] = hv;
            else             Vtg[bb + n * 64 + l] = hv;   // transposed [h][m]
          }
        }
      }
    } else {
      // ---- conv unit: [16 x 1024] * [1024 x 224] ----
      int nt = u - 42, o = nt * 16 + li;
      const _Float16* wrow = Wcb + o * 1024 + 8 * g;
      f32x4 acc[4] = {};
#pragma unroll 4
      for (int kk = 0; kk < 32; kk++) {
        f16x8 bf = *(const f16x8*)(wrow + 32 * kk);
        int i1 = kk * 8 + 2 * g;
        int i2 = i1 + 1;
#pragma unroll
        for (int bt = 0; bt < 4; bt++) {
          const _Float16* xt = Xl + bt * 16896;
          union { f16x4 h[2]; f16x8 v; } af;
          af.h[0] = *(const f16x4*)(xt + (i1 >> 2) * 264 + ((i1 & 3) << 6) + 4 * li);
          af.h[1] = *(const f16x4*)(xt + (i2 >> 2) * 264 + ((i2 & 3) << 6) + 4 * li);
          acc[bt] = MFMA(af.v, bf, acc[bt]);
        }
      }
      if (o < 200) {
        float cb = convb[o];
#pragma unroll
        for (int bt = 0; bt < 4; bt++) {
          float* ob = out + (size_t)(b0 + bt) * 3200 + o * 16;
#pragma unroll
          for (int r = 0; r < 4; r++) ob[4 * g + r] = acc[bt][r] + cb;
        }
      }
    }
  }
}

// ---- K3: attention per batch ------------------------------------------------
// LDS: Qs[64][232] @0 (29696) | Ks[64][232] @29696 | Sb[64][72] @59392 (9216)
// overlays: Sf[64][65] f32 @0 (after scores) ; Vt[224][64] swizzled @29696
//           Po[200][17] f32 @0 (after softmax)
// total 68608 -> 2 blocks/CU.
#define K3_LDS 68608
__global__ __launch_bounds__(256, 2) void k3_attn(
    const _Float16* __restrict__ Qg, const _Float16* __restrict__ Kg,
    const _Float16* __restrict__ Vtg, float* __restrict__ out) {
  extern __shared__ char smem[];
  _Float16* Qs = (_Float16*)smem;             // [64][232]
  _Float16* Ks = (_Float16*)(smem + 29696);   // [64][232]
  float*    Sf = (float*)smem;                // [64][65]
  _Float16* Vt = (_Float16*)(smem + 29696);   // [224][64] xor-swizzled
  _Float16* Sb = (_Float16*)(smem + 59392);   // [64][72]
  float*    Po = (float*)smem;                // [200][17]

  const int b = blockIdx.x;
  const int tid = threadIdx.x, lane = tid & 63, wave = tid >> 6;
  const int li = lane & 15, g = lane >> 4;
  const size_t bb = (size_t)b * 14336;

  // stage Q,K -> LDS; V -> registers (latency hidden under scores)
#pragma unroll
  for (int i = 0; i < 7; i++) {
    int j = tid + 256 * i;
    f16x8 q = *(const f16x8*)(Qg + bb + j * 8);
    int row = j / 28, col = (j % 28) * 8;
    *(f16x8*)(Qs + row * 232 + col) = q;
  }
#pragma unroll
  for (int i = 0; i < 7; i++) {
    int j = tid + 256 * i;
    f16x8 k = *(const f16x8*)(Kg + bb + j * 8);
    int row = j / 28, col = (j % 28) * 8;
    *(f16x8*)(Ks + row * 232 + col) = k;
  }
  f16x8 vreg[7];
#pragma unroll
  for (int i = 0; i < 7; i++)
    vreg[i] = *(const f16x8*)(Vtg + bb + (tid + 256 * i) * 8);
  __syncthreads();

  // scores: wave owns m-tile row mt=wave; S tiles in registers
  f32x4 sacc[4] = {};
  {
    const int mt = wave;
#pragma unroll
    for (int kk = 0; kk < 7; kk++) {
      f16x8 qa = *(const f16x8*)(Qs + (mt * 16 + li) * 232 + kk * 32 + 8 * g);
#pragma unroll
      for (int nt = 0; nt < 4; nt++) {
        f16x8 kb = *(const f16x8*)(Ks + (nt * 16 + li) * 232 + kk * 32 + 8 * g);
        sacc[nt] = MFMA(qa, kb, sacc[nt]);
      }
    }
  }
  __syncthreads();   // Q,K dead -> Sf/Vt regions writable

  {
    const int mt = wave;
#pragma unroll
    for (int nt = 0; nt < 4; nt++)
#pragma unroll
      for (int r = 0; r < 4; r++)
        Sf[(mt * 16 + 4 * g + r) * 65 + nt * 16 + li] = sacc[nt][r];
  }
#pragma unroll
  for (int i = 0; i < 7; i++) {
    int j = tid + 256 * i;
    int h = j >> 3, c = j & 7;
    *(f16x8*)(Vt + h * 64 + ((c ^ (h & 7)) << 3)) = vreg[i];
  }
  __syncthreads();

  // softmax over axis l (dim=1): per column m, 4 threads/column
  {
    int m = tid >> 2, r4 = tid & 3;
    float vals[16], mx = -1e30f;
#pragma unroll
    for (int i2 = 0; i2 < 16; i2++) {
      float v = Sf[(r4 + 4 * i2) * 65 + m];
      vals[i2] = v; mx = fmaxf(mx, v);
    }
    mx = fmaxf(mx, __shfl_xor(mx, 1));
    mx = fmaxf(mx, __shfl_xor(mx, 2));
    float s = 0.f;
#pragma unroll
    for (int i2 = 0; i2 < 16; i2++) { vals[i2] = __expf(vals[i2] - mx); s += vals[i2]; }
    s += __shfl_xor(s, 1);
    s += __shfl_xor(s, 2);
    float inv = 1.f / s;
#pragma unroll
    for (int i2 = 0; i2 < 16; i2++)
      Sb[(r4 + 4 * i2) * 72 + m] = (_Float16)(vals[i2] * inv);
  }
  __syncthreads();   // Sf dead

  for (int i = tid; i < 3400; i += 256) ((float*)smem)[i] = 0.f;  // zero Po
  __syncthreads();

  // PV + pooled accumulation. P-fragments shared across all ntl tiles: hoist.
  f16x8 pa[2][4];
#pragma unroll
  for (int kk = 0; kk < 2; kk++)
#pragma unroll
    for (int mt = 0; mt < 4; mt++)
      pa[kk][mt] = *(const f16x8*)(Sb + (mt * 16 + li) * 72 + kk * 32 + 8 * g);

  for (int ntl = wave; ntl < 14; ntl += 4) {
    int h = ntl * 16 + li;
    f16x8 vb[2];
#pragma unroll
    for (int kk = 0; kk < 2; kk++) {
      int cm = 4 * kk + g;
      vb[kk] = *(const f16x8*)(Vt + h * 64 + ((cm ^ (h & 7)) << 3));
    }
    f32x4 pacc[4] = {};
#pragma unroll
    for (int kk = 0; kk < 2; kk++)
#pragma unroll
      for (int mt = 0; mt < 4; mt++)
        pacc[mt] = MFMA(pa[kk][mt], vb[kk], pacc[mt]);
    if (h < 200) {
#pragma unroll
      for (int mt = 0; mt < 4; mt++)
#pragma unroll
        for (int r = 0; r < 4; r++) {
          int l = mt * 16 + 4 * g + r;
          int f = l * 200 + h;
          atomicAdd(&Po[(f >> 6) * 17 + (f & 15)], 0.25f * pacc[mt][r]);
        }
    }
  }
  __syncthreads();

  float* ob = out + (size_t)b * 3200;
  for (int t = tid; t < 3200; t += 256) {
    int c = t >> 4;
    ob[t] += Po[c * 17 + (t & 15)];
  }
}

// ---- fallback: round-2 fused kernel (known-good 533us), used if ws too small
#define FB_LDS 151296
__global__ __launch_bounds__(512, 2) void fused_fallback(
    const float* __restrict__ x, const _Float16* __restrict__ Wb,
    const _Float16* __restrict__ Wcb, const float* __restrict__ biasp,
    const float* __restrict__ convb, float* __restrict__ out) {
  extern __shared__ char smem[];
  _Float16* Xl = (_Float16*)smem;            // [64][264]
  _Float16* Qs = (_Float16*)(smem + 33792);  // [64][232]
  _Float16* Ks = (_Float16*)(smem + 63488);  // [64][232]
  _Float16* Vt = (_Float16*)(smem + 93184);  // [224][72]
  float* Sf    = (float*)(smem + 125440);    // [64][65]
  _Float16* Sb = (_Float16*)(smem + 142080); // [64][72]
  float* SA    = (float*)(smem + 33792);     // [64][228]
  float* Cv    = (float*)(smem + 125440);    // [16][226]

  const int b = blockIdx.x;
  const int tid = threadIdx.x;
  const int lane = tid & 63;
  const int wave = tid >> 6;
  const int li = lane & 15;
  const int g = lane >> 4;

  const float* xb = x + (size_t)b * 16384;
  for (int i = tid; i < 4096; i += 512) {
    float4 v = ((const float4*)xb)[i];
    int e = i * 4;
    int l = e >> 8, d = e & 255;
    f16x4 h;
    h.x = (_Float16)v.x; h.y = (_Float16)v.y;
    h.z = (_Float16)v.z; h.w = (_Float16)v.w;
    *(f16x4*)(Xl + l * 264 + d) = h;
  }
  __syncthreads();

  for (int u = wave; u < 42; u += 8) {
    int p = u / 14, nt = u % 14;
    int n = nt * 16 + li;
    const _Float16* wrow = Wb + p * 57344 + n * 256 + 8 * g;
    f16x8 bfr[8];
#pragma unroll
    for (int kk = 0; kk < 8; kk++) bfr[kk] = *(const f16x8*)(wrow + kk * 32);
    float bias = biasp[p * 224 + n];
    for (int m = 0; m < 4; m++) {
      f32x4 acc = {0.f, 0.f, 0.f, 0.f};
      const _Float16* arow = Xl + (m * 16 + li) * 264 + 8 * g;
#pragma unroll
      for (int kk = 0; kk < 8; kk++) acc = MFMA(*(const f16x8*)(arow + kk * 32), bfr[kk], acc);
#pragma unroll
      for (int r = 0; r < 4; r++) {
        int row = m * 16 + 4 * g + r;
        float v = acc[r] + bias;
        v = v > 0.f ? v : 0.f;
        _Float16 hv = (_Float16)v;
        if (p == 0) Qs[row * 232 + n] = hv;
        else if (p == 1) Ks[row * 232 + n] = hv;
        else Vt[n * 72 + row] = hv;
      }
    }
  }
  __syncthreads();

  for (int t = wave * 2; t < wave * 2 + 2; t++) {
    int mt = t >> 2, nt = t & 3;
    f32x4 acc = {0.f, 0.f, 0.f, 0.f};
    const _Float16* qrow = Qs + (mt * 16 + li) * 232 + 8 * g;
    const _Float16* krow = Ks + (nt * 16 + li) * 232 + 8 * g;
#pragma unroll
    for (int kk = 0; kk < 7; kk++)
      acc = MFMA(*(const f16x8*)(qrow + kk * 32), *(const f16x8*)(krow + kk * 32), acc);
#pragma unroll
    for (int r = 0; r < 4; r++)
      Sf[(mt * 16 + 4 * g + r) * 65 + nt * 16 + li] = acc[r];
  }
  __syncthreads();

  {
    int m = tid >> 3, r = tid & 7;
    float vals[8];
    float mx = -1e30f;
#pragma unroll
    for (int i = 0; i < 8; i++) {
      float v = Sf[(r + 8 * i) * 65 + m];
      vals[i] = v;
      mx = fmaxf(mx, v);
    }
    mx = fmaxf(mx, __shfl_xor(mx, 1));
    mx = fmaxf(mx, __shfl_xor(mx, 2));
    mx = fmaxf(mx, __shfl_xor(mx, 4));
    float s = 0.f;
#pragma unroll
    for (int i = 0; i < 8; i++) { vals[i] = __expf(vals[i] - mx); s += vals[i]; }
    s += __shfl_xor(s, 1);
    s += __shfl_xor(s, 2);
    s += __shfl_xor(s, 4);
    float inv = 1.0f / s;
#pragma unroll
    for (int i = 0; i < 8; i++)
      Sb[(r + 8 * i) * 72 + m] = (_Float16)(vals[i] * inv);
  }
  __syncthreads();

  for (int nt = wave; nt < 14; nt += 8) {
    int o = nt * 16 + li;
    const _Float16* wrow = Wcb + o * 1024 + 8 * g;
    f32x4 acc = {0.f, 0.f, 0.f, 0.f};
#pragma unroll 4
    for (int kk = 0; kk < 32; kk++) {
      int i1 = kk * 8 + 2 * g;
      int i2 = i1 + 1;
      union { f16x4 h[2]; f16x8 v; } af;
      af.h[0] = *(const f16x4*)(Xl + (i1 >> 2) * 264 + ((i1 & 3) << 6) + 4 * li);
      af.h[1] = *(const f16x4*)(Xl + (i2 >> 2) * 264 + ((i2 & 3) << 6) + 4 * li);
      acc = MFMA(af.v, *(const f16x8*)(wrow + 32 * kk), acc);
    }
#pragma unroll
    for (int r = 0; r < 4; r++) Cv[(4 * g + r) * 226 + o] = acc[r];
  }

  for (int t = wave; t < 56; t += 8) {
    int mt = t / 14, nt = t % 14;
    f32x4 acc = {0.f, 0.f, 0.f, 0.f};
    const _Float16* arow = Sb + (mt * 16 + li) * 72 + 8 * g;
    const _Float16* brow = Vt + (nt * 16 + li) * 72 + 8 * g;
#pragma unroll
    for (int kk = 0; kk < 2; kk++)
      acc = MFMA(*(const f16x8*)(arow + kk * 32), *(const f16x8*)(brow + kk * 32), acc);
#pragma unroll
    for (int r = 0; r < 4; r++)
      SA[(mt * 16 + 4 * g + r) * 228 + (nt * 16 + li)] = acc[r];
  }
  __syncthreads();

  float* ob = out + (size_t)b * 3200;
  for (int t = tid; t < 3200; t += 512) {
    int c = t >> 4, s = t & 15;
    float cv = Cv[s * 226 + c] + convb[c];
    float pool = 0.f;
#pragma unroll
    for (int j = 0; j < 4; j++) {
      int flat = c * 64 + j * 16 + s;
      int l = flat / 200;
      int h = flat - l * 200;
      pool += SA[l * 228 + h];
    }
    ob[t] = cv + 0.25f * pool;
  }
}

// ---- launch -----------------------------------------------------------------
extern "C" void kernel_launch(void* const* d_in, const int* in_sizes, int n_in,
                              void* d_out, int out_size, void* d_ws, size_t ws_size,
                              hipStream_t stream) {
  const float* x  = (const float*)d_in[0];
  const float* Wq = (const float*)d_in[1];
  const float* bq = (const float*)d_in[2];
  const float* Wk = (const float*)d_in[3];
  const float* bk = (const float*)d_in[4];
  const float* Wv = (const float*)d_in[5];
  const float* bv = (const float*)d_in[6];
  const float* cw = (const float*)d_in[7];
  const float* cb = (const float*)d_in[8];

  char* ws = (char*)d_ws;
  _Float16* Wb  = (_Float16*)ws;             // 344064 B
  _Float16* Wcb = (_Float16*)(ws + 344064);  // 458752 B
  float* biasp  = (float*)(ws + 802816);     // 2688 B

  hipLaunchKernelGGL(wcvt, dim3(512), dim3(256), 0, stream,
                     Wq, Wk, Wv, cw, bq, bk, bv, Wb, Wcb, biasp);

  const size_t QKV_BASE = 805888ull;
  const size_t QKV_ONE  = 117440512ull;           // 4096*64*224*2
  const size_t NEED = QKV_BASE + 3ull * QKV_ONE;  // ~353 MB

  if (ws_size >= NEED) {
    _Float16* Qg  = (_Float16*)(ws + QKV_BASE);
    _Float16* Kg  = (_Float16*)(ws + QKV_BASE + QKV_ONE);
    _Float16* Vtg = (_Float16*)(ws + QKV_BASE + 2 * QKV_ONE);

    hipFuncSetAttribute((const void*)k1_proj_conv,
                        hipFuncAttributeMaxDynamicSharedMemorySize, 135168);
    hipLaunchKernelGGL(k1_proj_conv, dim3(1024), dim3(512), 135168, stream,
                       x, Wb, Wcb, biasp, cb, Qg, Kg, Vtg, (float*)d_out);

    hipFuncSetAttribute((const void*)k3_attn,
                        hipFuncAttributeMaxDynamicSharedMemorySize, K3_LDS);
    hipLaunchKernelGGL(k3_attn, dim3(4096), dim3(256), K3_LDS, stream,
                       Qg, Kg, Vtg, (float*)d_out);
  } else {
    hipFuncSetAttribute((const void*)fused_fallback,
                        hipFuncAttributeMaxDynamicSharedMemorySize, FB_LDS);
    hipLaunchKernelGGL(fused_fallback, dim3(4096), dim3(512), FB_LDS, stream,
                       x, Wb, Wcb, biasp, cb, (float*)d_out);
  }
}

// Round 6
// 584.931 us; speedup vs baseline: 1.8439x; 1.0680x over previous
//
#include <hip/hip_runtime.h>

typedef _Float16 f16x8 __attribute__((ext_vector_type(8)));
typedef _Float16 f16x4 __attribute__((ext_vector_type(4)));
typedef float f32x4 __attribute__((ext_vector_type(4)));

static __device__ __forceinline__ f32x4 MFMA(f16x8 a, f16x8 b, f32x4 c) {
  return __builtin_amdgcn_mfma_f32_16x16x32_f16(a, b, c, 0, 0, 0);
}

// ---- weight conversion pre-kernel ------------------------------------------
// ws layout:
//   Wb   : 3 x [224][256] f16  (Wq,Wk,Wv; rows >=200 zero)      @ 0       (344064 B)
//   Wcb  : [224][1024] f16     (conv_w flat; rows >=200 zero)   @ 344064  (458752 B)
//   biasp: 3 x [224] f32       (bq,bk,bv padded w/ zeros)       @ 802816  (2688 B)
//   Qg   : [4096][64][224] f16                                  @ 805888
//   Kg   : [4096][64][224] f16                                  @ 805888+117440512
//   Vtg  : [4096][224][64] f16                                  @ 805888+234881024
__global__ void wcvt(const float* __restrict__ Wq, const float* __restrict__ Wk,
                     const float* __restrict__ Wv, const float* __restrict__ cw,
                     const float* __restrict__ bq, const float* __restrict__ bk,
                     const float* __restrict__ bv,
                     _Float16* __restrict__ Wb,
                     _Float16* __restrict__ Wcb,
                     float* __restrict__ biasp) {
  int gt = blockIdx.x * blockDim.x + threadIdx.x;
  int gs = gridDim.x * blockDim.x;
  const int WN = 224 * 256;
  for (int i = gt; i < WN; i += gs) {
    int n = i >> 8;
    Wb[i]          = (n < 200) ? (_Float16)Wq[i] : (_Float16)0.f;
    Wb[WN + i]     = (n < 200) ? (_Float16)Wk[i] : (_Float16)0.f;
    Wb[2 * WN + i] = (n < 200) ? (_Float16)Wv[i] : (_Float16)0.f;
  }
  for (int i = gt; i < 224 * 1024; i += gs) {
    int o = i >> 10;
    Wcb[i] = (o < 200) ? (_Float16)cw[i] : (_Float16)0.f;
  }
  for (int i = gt; i < 224; i += gs) {
    biasp[i]       = (i < 200) ? bq[i] : 0.f;
    biasp[224 + i] = (i < 200) ? bk[i] : 0.f;
    biasp[448 + i] = (i < 200) ? bv[i] : 0.f;
  }
}

// ---- K1 v2: projections + conv, 2 batches per block, 2 blocks/CU ------------
// LDS: Xl 2 x [64][264] f16 = 67584 B. One barrier total.
// 56 units: Q=0..13, K=14..27 (swapped operands -> f16x4 stores along n),
//           V=28..41 (normal operands -> f16x4 stores along l),
//           conv=42..55 (float4 stores).
__global__ __launch_bounds__(512, 4) void k1_proj_conv(
    const float* __restrict__ x, const _Float16* __restrict__ Wb,
    const _Float16* __restrict__ Wcb, const float* __restrict__ biasp,
    const float* __restrict__ convb,
    _Float16* __restrict__ Qg, _Float16* __restrict__ Kg,
    _Float16* __restrict__ Vtg, float* __restrict__ out) {
  extern __shared__ char smem[];
  _Float16* Xl = (_Float16*)smem;  // 2 x [64][264]
  const int tid = threadIdx.x, lane = tid & 63, wave = tid >> 6;
  const int li = lane & 15, g = lane >> 4;
  const int b0 = blockIdx.x * 2;

  // stage x for 2 batches (coalesced float4, f32->f16)
  const float* xb = x + (size_t)b0 * 16384;
#pragma unroll
  for (int j = 0; j < 16; j++) {
    int f = tid + 512 * j;               // float4 idx over 2 batches
    float4 v = ((const float4*)xb)[f];
    int bt = f >> 12, rem = f & 4095, l = rem >> 6, c4 = rem & 63;
    f16x4 h;
    h.x = (_Float16)v.x; h.y = (_Float16)v.y;
    h.z = (_Float16)v.z; h.w = (_Float16)v.w;
    *(f16x4*)(Xl + bt * 16896 + l * 264 + c4 * 4) = h;
  }
  __syncthreads();

#pragma unroll 1
  for (int i = 0; i < 7; i++) {
    int u = wave + 8 * i;
    if (u < 28) {
      // ---- Q/K unit, swapped operands: D[n][l] ----
      int p = u / 14, nt = u % 14;
      const _Float16* wrow = Wb + p * 57344 + (nt * 16 + li) * 256 + 8 * g;
      f32x4 acc[2][4] = {};
#pragma unroll
      for (int kk = 0; kk < 8; kk++) {
        f16x8 aw = *(const f16x8*)(wrow + 32 * kk);
#pragma unroll
        for (int bt = 0; bt < 2; bt++)
#pragma unroll
          for (int mt = 0; mt < 4; mt++) {
            f16x8 bx = *(const f16x8*)(Xl + bt * 16896 + (mt * 16 + li) * 264 + 32 * kk + 8 * g);
            acc[bt][mt] = MFMA(aw, bx, acc[bt][mt]);
          }
      }
      float4 b4 = *(const float4*)(biasp + p * 224 + nt * 16 + 4 * g);
      _Float16* dst0 = (p == 0) ? Qg : Kg;
#pragma unroll
      for (int bt = 0; bt < 2; bt++) {
        _Float16* db = dst0 + (size_t)(b0 + bt) * 14336;
#pragma unroll
        for (int mt = 0; mt < 4; mt++) {
          f16x4 hv;
          {
            float v0 = acc[bt][mt][0] + b4.x; hv[0] = (_Float16)(v0 > 0.f ? v0 : 0.f);
            float v1 = acc[bt][mt][1] + b4.y; hv[1] = (_Float16)(v1 > 0.f ? v1 : 0.f);
            float v2 = acc[bt][mt][2] + b4.z; hv[2] = (_Float16)(v2 > 0.f ? v2 : 0.f);
            float v3 = acc[bt][mt][3] + b4.w; hv[3] = (_Float16)(v3 > 0.f ? v3 : 0.f);
          }
          *(f16x4*)(db + (mt * 16 + li) * 224 + nt * 16 + 4 * g) = hv;
        }
      }
    } else if (u < 42) {
      // ---- V unit, normal operands: D[l][h]; store transposed [h][l] ----
      int nt = u - 28;
      const _Float16* wrow = Wb + 2 * 57344 + (nt * 16 + li) * 256 + 8 * g;
      f32x4 acc[2][4] = {};
#pragma unroll
      for (int kk = 0; kk < 8; kk++) {
        f16x8 bw = *(const f16x8*)(wrow + 32 * kk);
#pragma unroll
        for (int bt = 0; bt < 2; bt++)
#pragma unroll
          for (int mt = 0; mt < 4; mt++) {
            f16x8 ax = *(const f16x8*)(Xl + bt * 16896 + (mt * 16 + li) * 264 + 32 * kk + 8 * g);
            acc[bt][mt] = MFMA(ax, bw, acc[bt][mt]);
          }
      }
      float bias = biasp[448 + nt * 16 + li];
#pragma unroll
      for (int bt = 0; bt < 2; bt++) {
        _Float16* db = Vtg + (size_t)(b0 + bt) * 14336;
#pragma unroll
        for (int mt = 0; mt < 4; mt++) {
          f16x4 hv;
#pragma unroll
          for (int r = 0; r < 4; r++) {
            float v = acc[bt][mt][r] + bias;
            hv[r] = (_Float16)(v > 0.f ? v : 0.f);
          }
          *(f16x4*)(db + (nt * 16 + li) * 64 + mt * 16 + 4 * g) = hv;
        }
      }
    } else {
      // ---- conv unit: [16 x 1024] * [1024 x 224] ----
      int nt = u - 42, o = nt * 16 + li;
      const _Float16* wrow = Wcb + o * 1024 + 8 * g;
      f32x4 acc[2] = {};
#pragma unroll 4
      for (int kk = 0; kk < 32; kk++) {
        f16x8 bf = *(const f16x8*)(wrow + 32 * kk);
        int i1 = kk * 8 + 2 * g;
        int i2 = i1 + 1;
#pragma unroll
        for (int bt = 0; bt < 2; bt++) {
          const _Float16* xt = Xl + bt * 16896;
          union { f16x4 h[2]; f16x8 v; } af;
          af.h[0] = *(const f16x4*)(xt + (i1 >> 2) * 264 + ((i1 & 3) << 6) + 4 * li);
          af.h[1] = *(const f16x4*)(xt + (i2 >> 2) * 264 + ((i2 & 3) << 6) + 4 * li);
          acc[bt] = MFMA(af.v, bf, acc[bt]);
        }
      }
      if (o < 200) {
        float cb = convb[o];
#pragma unroll
        for (int bt = 0; bt < 2; bt++) {
          float4 vo;
          vo.x = acc[bt][0] + cb; vo.y = acc[bt][1] + cb;
          vo.z = acc[bt][2] + cb; vo.w = acc[bt][3] + cb;
          *(float4*)(out + (size_t)(b0 + bt) * 3200 + o * 16 + 4 * g) = vo;
        }
      }
    }
  }
}

// ---- K3: attention per batch (unchanged from round 5) -----------------------
// LDS: Qs[64][232] @0 (29696) | Ks[64][232] @29696 | Sb[64][72] @59392 (9216)
// overlays: Sf[64][65] f32 @0 (after scores) ; Vt[224][64] swizzled @29696
//           Po[200][17] f32 @0 (after softmax)
// total 68608 -> 2 blocks/CU.
#define K3_LDS 68608
__global__ __launch_bounds__(256, 2) void k3_attn(
    const _Float16* __restrict__ Qg, const _Float16* __restrict__ Kg,
    const _Float16* __restrict__ Vtg, float* __restrict__ out) {
  extern __shared__ char smem[];
  _Float16* Qs = (_Float16*)smem;             // [64][232]
  _Float16* Ks = (_Float16*)(smem + 29696);   // [64][232]
  float*    Sf = (float*)smem;                // [64][65]
  _Float16* Vt = (_Float16*)(smem + 29696);   // [224][64] xor-swizzled
  _Float16* Sb = (_Float16*)(smem + 59392);   // [64][72]
  float*    Po = (float*)smem;                // [200][17]

  const int b = blockIdx.x;
  const int tid = threadIdx.x, lane = tid & 63, wave = tid >> 6;
  const int li = lane & 15, g = lane >> 4;
  const size_t bb = (size_t)b * 14336;

  // stage Q,K -> LDS; V -> registers (latency hidden under scores)
#pragma unroll
  for (int i = 0; i < 7; i++) {
    int j = tid + 256 * i;
    f16x8 q = *(const f16x8*)(Qg + bb + j * 8);
    int row = j / 28, col = (j % 28) * 8;
    *(f16x8*)(Qs + row * 232 + col) = q;
  }
#pragma unroll
  for (int i = 0; i < 7; i++) {
    int j = tid + 256 * i;
    f16x8 k = *(const f16x8*)(Kg + bb + j * 8);
    int row = j / 28, col = (j % 28) * 8;
    *(f16x8*)(Ks + row * 232 + col) = k;
  }
  f16x8 vreg[7];
#pragma unroll
  for (int i = 0; i < 7; i++)
    vreg[i] = *(const f16x8*)(Vtg + bb + (tid + 256 * i) * 8);
  __syncthreads();

  // scores: wave owns m-tile row mt=wave; S tiles in registers
  f32x4 sacc[4] = {};
  {
    const int mt = wave;
#pragma unroll
    for (int kk = 0; kk < 7; kk++) {
      f16x8 qa = *(const f16x8*)(Qs + (mt * 16 + li) * 232 + kk * 32 + 8 * g);
#pragma unroll
      for (int nt = 0; nt < 4; nt++) {
        f16x8 kb = *(const f16x8*)(Ks + (nt * 16 + li) * 232 + kk * 32 + 8 * g);
        sacc[nt] = MFMA(qa, kb, sacc[nt]);
      }
    }
  }
  __syncthreads();   // Q,K dead -> Sf/Vt regions writable

  {
    const int mt = wave;
#pragma unroll
    for (int nt = 0; nt < 4; nt++)
#pragma unroll
      for (int r = 0; r < 4; r++)
        Sf[(mt * 16 + 4 * g + r) * 65 + nt * 16 + li] = sacc[nt][r];
  }
#pragma unroll
  for (int i = 0; i < 7; i++) {
    int j = tid + 256 * i;
    int h = j >> 3, c = j & 7;
    *(f16x8*)(Vt + h * 64 + ((c ^ (h & 7)) << 3)) = vreg[i];
  }
  __syncthreads();

  // softmax over axis l (dim=1): per column m, 4 threads/column
  {
    int m = tid >> 2, r4 = tid & 3;
    float vals[16], mx = -1e30f;
#pragma unroll
    for (int i2 = 0; i2 < 16; i2++) {
      float v = Sf[(r4 + 4 * i2) * 65 + m];
      vals[i2] = v; mx = fmaxf(mx, v);
    }
    mx = fmaxf(mx, __shfl_xor(mx, 1));
    mx = fmaxf(mx, __shfl_xor(mx, 2));
    float s = 0.f;
#pragma unroll
    for (int i2 = 0; i2 < 16; i2++) { vals[i2] = __expf(vals[i2] - mx); s += vals[i2]; }
    s += __shfl_xor(s, 1);
    s += __shfl_xor(s, 2);
    float inv = 1.f / s;
#pragma unroll
    for (int i2 = 0; i2 < 16; i2++)
      Sb[(r4 + 4 * i2) * 72 + m] = (_Float16)(vals[i2] * inv);
  }
  __syncthreads();   // Sf dead

  for (int i = tid; i < 3400; i += 256) ((float*)smem)[i] = 0.f;  // zero Po
  __syncthreads();

  // PV + pooled accumulation. P-fragments shared across all ntl tiles: hoist.
  f16x8 pa[2][4];
#pragma unroll
  for (int kk = 0; kk < 2; kk++)
#pragma unroll
    for (int mt = 0; mt < 4; mt++)
      pa[kk][mt] = *(const f16x8*)(Sb + (mt * 16 + li) * 72 + kk * 32 + 8 * g);

  for (int ntl = wave; ntl < 14; ntl += 4) {
    int h = ntl * 16 + li;
    f16x8 vb[2];
#pragma unroll
    for (int kk = 0; kk < 2; kk++) {
      int cm = 4 * kk + g;
      vb[kk] = *(const f16x8*)(Vt + h * 64 + ((cm ^ (h & 7)) << 3));
    }
    f32x4 pacc[4] = {};
#pragma unroll
    for (int kk = 0; kk < 2; kk++)
#pragma unroll
      for (int mt = 0; mt < 4; mt++)
        pacc[mt] = MFMA(pa[kk][mt], vb[kk], pacc[mt]);
    if (h < 200) {
#pragma unroll
      for (int mt = 0; mt < 4; mt++)
#pragma unroll
        for (int r = 0; r < 4; r++) {
          int l = mt * 16 + 4 * g + r;
          int f = l * 200 + h;
          atomicAdd(&Po[(f >> 6) * 17 + (f & 15)], 0.25f * pacc[mt][r]);
        }
    }
  }
  __syncthreads();

  float* ob = out + (size_t)b * 3200;
  for (int t = tid; t < 3200; t += 256) {
    int c = t >> 4;
    ob[t] += Po[c * 17 + (t & 15)];
  }
}

// ---- fallback: round-2 fused kernel (known-good 533us), used if ws too small
#define FB_LDS 151296
__global__ __launch_bounds__(512, 2) void fused_fallback(
    const float* __restrict__ x, const _Float16* __restrict__ Wb,
    const _Float16* __restrict__ Wcb, const float* __restrict__ biasp,
    const float* __restrict__ convb, float* __restrict__ out) {
  extern __shared__ char smem[];
  _Float16* Xl = (_Float16*)smem;            // [64][264]
  _Float16* Qs = (_Float16*)(smem + 33792);  // [64][232]
  _Float16* Ks = (_Float16*)(smem + 63488);  // [64][232]
  _Float16* Vt = (_Float16*)(smem + 93184);  // [224][72]
  float* Sf    = (float*)(smem + 125440);    // [64][65]
  _Float16* Sb = (_Float16*)(smem + 142080); // [64][72]
  float* SA    = (float*)(smem + 33792);     // [64][228]
  float* Cv    = (float*)(smem + 125440);    // [16][226]

  const int b = blockIdx.x;
  const int tid = threadIdx.x;
  const int lane = tid & 63;
  const int wave = tid >> 6;
  const int li = lane & 15;
  const int g = lane >> 4;

  const float* xb = x + (size_t)b * 16384;
  for (int i = tid; i < 4096; i += 512) {
    float4 v = ((const float4*)xb)[i];
    int e = i * 4;
    int l = e >> 8, d = e & 255;
    f16x4 h;
    h.x = (_Float16)v.x; h.y = (_Float16)v.y;
    h.z = (_Float16)v.z; h.w = (_Float16)v.w;
    *(f16x4*)(Xl + l * 264 + d) = h;
  }
  __syncthreads();

  for (int u = wave; u < 42; u += 8) {
    int p = u / 14, nt = u % 14;
    int n = nt * 16 + li;
    const _Float16* wrow = Wb + p * 57344 + n * 256 + 8 * g;
    f16x8 bfr[8];
#pragma unroll
    for (int kk = 0; kk < 8; kk++) bfr[kk] = *(const f16x8*)(wrow + kk * 32);
    float bias = biasp[p * 224 + n];
    for (int m = 0; m < 4; m++) {
      f32x4 acc = {0.f, 0.f, 0.f, 0.f};
      const _Float16* arow = Xl + (m * 16 + li) * 264 + 8 * g;
#pragma unroll
      for (int kk = 0; kk < 8; kk++) acc = MFMA(*(const f16x8*)(arow + kk * 32), bfr[kk], acc);
#pragma unroll
      for (int r = 0; r < 4; r++) {
        int row = m * 16 + 4 * g + r;
        float v = acc[r] + bias;
        v = v > 0.f ? v : 0.f;
        _Float16 hv = (_Float16)v;
        if (p == 0) Qs[row * 232 + n] = hv;
        else if (p == 1) Ks[row * 232 + n] = hv;
        else Vt[n * 72 + row] = hv;
      }
    }
  }
  __syncthreads();

  for (int t = wave * 2; t < wave * 2 + 2; t++) {
    int mt = t >> 2, nt = t & 3;
    f32x4 acc = {0.f, 0.f, 0.f, 0.f};
    const _Float16* qrow = Qs + (mt * 16 + li) * 232 + 8 * g;
    const _Float16* krow = Ks + (nt * 16 + li) * 232 + 8 * g;
#pragma unroll
    for (int kk = 0; kk < 7; kk++)
      acc = MFMA(*(const f16x8*)(qrow + kk * 32), *(const f16x8*)(krow + kk * 32), acc);
#pragma unroll
    for (int r = 0; r < 4; r++)
      Sf[(mt * 16 + 4 * g + r) * 65 + nt * 16 + li] = acc[r];
  }
  __syncthreads();

  {
    int m = tid >> 3, r = tid & 7;
    float vals[8];
    float mx = -1e30f;
#pragma unroll
    for (int i = 0; i < 8; i++) {
      float v = Sf[(r + 8 * i) * 65 + m];
      vals[i] = v;
      mx = fmaxf(mx, v);
    }
    mx = fmaxf(mx, __shfl_xor(mx, 1));
    mx = fmaxf(mx, __shfl_xor(mx, 2));
    mx = fmaxf(mx, __shfl_xor(mx, 4));
    float s = 0.f;
#pragma unroll
    for (int i = 0; i < 8; i++) { vals[i] = __expf(vals[i] - mx); s += vals[i]; }
    s += __shfl_xor(s, 1);
    s += __shfl_xor(s, 2);
    s += __shfl_xor(s, 4);
    float inv = 1.0f / s;
#pragma unroll
    for (int i = 0; i < 8; i++)
      Sb[(r + 8 * i) * 72 + m] = (_Float16)(vals[i] * inv);
  }
  __syncthreads();

  for (int nt = wave; nt < 14; nt += 8) {
    int o = nt * 16 + li;
    const _Float16* wrow = Wcb + o * 1024 + 8 * g;
    f32x4 acc = {0.f, 0.f, 0.f, 0.f};
#pragma unroll 4
    for (int kk = 0; kk < 32; kk++) {
      int i1 = kk * 8 + 2 * g;
      int i2 = i1 + 1;
      union { f16x4 h[2]; f16x8 v; } af;
      af.h[0] = *(const f16x4*)(Xl + (i1 >> 2) * 264 + ((i1 & 3) << 6) + 4 * li);
      af.h[1] = *(const f16x4*)(Xl + (i2 >> 2) * 264 + ((i2 & 3) << 6) + 4 * li);
      acc = MFMA(af.v, *(const f16x8*)(wrow + 32 * kk), acc);
    }
#pragma unroll
    for (int r = 0; r < 4; r++) Cv[(4 * g + r) * 226 + o] = acc[r];
  }

  for (int t = wave; t < 56; t += 8) {
    int mt = t / 14, nt = t % 14;
    f32x4 acc = {0.f, 0.f, 0.f, 0.f};
    const _Float16* arow = Sb + (mt * 16 + li) * 72 + 8 * g;
    const _Float16* brow = Vt + (nt * 16 + li) * 72 + 8 * g;
#pragma unroll
    for (int kk = 0; kk < 2; kk++)
      acc = MFMA(*(const f16x8*)(arow + kk * 32), *(const f16x8*)(brow + kk * 32), acc);
#pragma unroll
    for (int r = 0; r < 4; r++)
      SA[(mt * 16 + 4 * g + r) * 228 + (nt * 16 + li)] = acc[r];
  }
  __syncthreads();

  float* ob = out + (size_t)b * 3200;
  for (int t = tid; t < 3200; t += 512) {
    int c = t >> 4, s = t & 15;
    float cv = Cv[s * 226 + c] + convb[c];
    float pool = 0.f;
#pragma unroll
    for (int j = 0; j < 4; j++) {
      int flat = c * 64 + j * 16 + s;
      int l = flat / 200;
      int h = flat - l * 200;
      pool += SA[l * 228 + h];
    }
    ob[t] = cv + 0.25f * pool;
  }
}

// ---- launch -----------------------------------------------------------------
extern "C" void kernel_launch(void* const* d_in, const int* in_sizes, int n_in,
                              void* d_out, int out_size, void* d_ws, size_t ws_size,
                              hipStream_t stream) {
  const float* x  = (const float*)d_in[0];
  const float* Wq = (const float*)d_in[1];
  const float* bq = (const float*)d_in[2];
  const float* Wk = (const float*)d_in[3];
  const float* bk = (const float*)d_in[4];
  const float* Wv = (const float*)d_in[5];
  const float* bv = (const float*)d_in[6];
  const float* cw = (const float*)d_in[7];
  const float* cb = (const float*)d_in[8];

  char* ws = (char*)d_ws;
  _Float16* Wb  = (_Float16*)ws;             // 344064 B
  _Float16* Wcb = (_Float16*)(ws + 344064);  // 458752 B
  float* biasp  = (float*)(ws + 802816);     // 2688 B

  hipLaunchKernelGGL(wcvt, dim3(512), dim3(256), 0, stream,
                     Wq, Wk, Wv, cw, bq, bk, bv, Wb, Wcb, biasp);

  const size_t QKV_BASE = 805888ull;
  const size_t QKV_ONE  = 117440512ull;           // 4096*64*224*2
  const size_t NEED = QKV_BASE + 3ull * QKV_ONE;  // ~353 MB

  if (ws_size >= NEED) {
    _Float16* Qg  = (_Float16*)(ws + QKV_BASE);
    _Float16* Kg  = (_Float16*)(ws + QKV_BASE + QKV_ONE);
    _Float16* Vtg = (_Float16*)(ws + QKV_BASE + 2 * QKV_ONE);

    hipFuncSetAttribute((const void*)k1_proj_conv,
                        hipFuncAttributeMaxDynamicSharedMemorySize, 67584);
    hipLaunchKernelGGL(k1_proj_conv, dim3(2048), dim3(512), 67584, stream,
                       x, Wb, Wcb, biasp, cb, Qg, Kg, Vtg, (float*)d_out);

    hipFuncSetAttribute((const void*)k3_attn,
                        hipFuncAttributeMaxDynamicSharedMemorySize, K3_LDS);
    hipLaunchKernelGGL(k3_attn, dim3(4096), dim3(256), K3_LDS, stream,
                       Qg, Kg, Vtg, (float*)d_out);
  } else {
    hipFuncSetAttribute((const void*)fused_fallback,
                        hipFuncAttributeMaxDynamicSharedMemorySize, FB_LDS);
    hipLaunchKernelGGL(fused_fallback, dim3(4096), dim3(512), FB_LDS, stream,
                       x, Wb, Wcb, biasp, cb, (float*)d_out);
  }
}